// Round 1
// baseline (1019.903 us; speedup 1.0000x reference)
//
#include <hip/hip_runtime.h>
#include <hip/hip_bf16.h>
#include <math.h>

// ---------------------------------------------------------------------------
// InfNet: 2-layer GCN + Weibull epilogue, all-fp32 pipeline.
// Â = D^-1/2 (A + I) D^-1/2 applied as: out[i] = dinv[i]*(T[i]*dinv[i] + sum_e dinv[src]*T[src])
// ---------------------------------------------------------------------------

__global__ __launch_bounds__(256) void count_kernel(const int* __restrict__ dst,
                                                    int* __restrict__ cnt, int E)
{
    int e = blockIdx.x * blockDim.x + threadIdx.x;
    if (e < E) atomicAdd(&cnt[dst[e]], 1);
}

__global__ __launch_bounds__(256) void dinv_kernel(const int* __restrict__ cnt,
                                                   float* __restrict__ dinv, int N)
{
    int i = blockIdx.x * blockDim.x + threadIdx.x;
    if (i < N) dinv[i] = 1.0f / sqrtf((float)(cnt[i] + 1));   // +1 self-loop
}

// single-block exclusive scan over N counts -> rowptr, cursor
__global__ __launch_bounds__(1024) void scan_kernel(const int* __restrict__ cnt,
                                                    int* __restrict__ rowptr,
                                                    int* __restrict__ cursor, int N)
{
    __shared__ int sdata[1024];
    __shared__ int carry_s;
    int tid = threadIdx.x;
    if (tid == 0) carry_s = 0;
    __syncthreads();
    for (int base = 0; base < N; base += 1024) {
        int i = base + tid;
        int v = (i < N) ? cnt[i] : 0;
        sdata[tid] = v;
        __syncthreads();
        for (int off = 1; off < 1024; off <<= 1) {
            int t = (tid >= off) ? sdata[tid - off] : 0;
            __syncthreads();
            sdata[tid] += t;
            __syncthreads();
        }
        int incl  = sdata[tid];
        int total = sdata[1023];
        int excl  = incl - v + carry_s;
        if (i < N) { rowptr[i] = excl; cursor[i] = excl; }
        __syncthreads();
        if (tid == 0) carry_s += total;
        __syncthreads();
    }
    if (tid == 0) rowptr[N] = carry_s;
}

__global__ __launch_bounds__(256) void scatter_kernel(const int* __restrict__ src,
                                                      const int* __restrict__ dst,
                                                      int* __restrict__ cursor,
                                                      int* __restrict__ col, int E)
{
    int e = blockIdx.x * blockDim.x + threadIdx.x;
    if (e < E) {
        int d = dst[e];
        int pos = atomicAdd(&cursor[d], 1);
        col[pos] = src[e];
    }
}

// split W1 (256x129) into W1main (256x128) and W1col (256) so GEMM2 B-rows are
// 16B-aligned for float4 staging.
__global__ __launch_bounds__(256) void repack_w1(const float* __restrict__ W1,
                                                 float* __restrict__ W1main,
                                                 float* __restrict__ W1col)
{
    int i = blockIdx.x * blockDim.x + threadIdx.x;
    if (i < 256 * 129) {
        int k = i / 129, j = i % 129;
        float v = W1[i];
        if (j == 128) W1col[k] = v;
        else          W1main[k * 128 + j] = v;
    }
}

// fp32 tiled GEMM: C(MxN) = A(MxK) * B(KxN). BM=BN=128, BK=16, 256 thr, 8x8/thread.
#define BM 128
#define BN 128
#define BKK 16
__global__ __launch_bounds__(256) void gemm_f32(const float* __restrict__ A,
                                                const float* __restrict__ B,
                                                float* __restrict__ C,
                                                int M, int N, int K,
                                                int lda, int ldb, int ldc)
{
    __shared__ float As[BKK][BM + 4];   // row stride 132 floats = 33*16B -> aligned
    __shared__ float Bs[BKK][BN + 8];   // row stride 136 floats = 34*16B -> aligned

    int tid = threadIdx.x;
    int bm = blockIdx.x * BM;
    int bn = blockIdx.y * BN;
    int tx = tid & 15;
    int ty = tid >> 4;

    float acc[8][8];
#pragma unroll
    for (int i = 0; i < 8; ++i)
#pragma unroll
        for (int j = 0; j < 8; ++j) acc[i][j] = 0.f;

    int arow = tid >> 2;          // 0..63
    int akq  = (tid & 3) * 4;     // 0,4,8,12
    int bkr  = tid >> 5;          // 0..7
    int bcq  = (tid & 31) * 4;    // 0..124

    for (int k0 = 0; k0 < K; k0 += BKK) {
#pragma unroll
        for (int p = 0; p < 2; ++p) {
            int r  = arow + p * 64;
            int gr = bm + r;
            float4 v = make_float4(0.f, 0.f, 0.f, 0.f);
            if (gr < M) v = *reinterpret_cast<const float4*>(&A[(size_t)gr * lda + k0 + akq]);
            As[akq + 0][r] = v.x;
            As[akq + 1][r] = v.y;
            As[akq + 2][r] = v.z;
            As[akq + 3][r] = v.w;
        }
#pragma unroll
        for (int p = 0; p < 2; ++p) {
            int kr = bkr + p * 8;
            float4 v = *reinterpret_cast<const float4*>(&B[(size_t)(k0 + kr) * ldb + bn + bcq]);
            *reinterpret_cast<float4*>(&Bs[kr][bcq]) = v;
        }
        __syncthreads();
#pragma unroll
        for (int kk = 0; kk < BKK; ++kk) {
            float4 a0 = *reinterpret_cast<const float4*>(&As[kk][ty * 4]);
            float4 a1 = *reinterpret_cast<const float4*>(&As[kk][ty * 4 + 64]);
            float4 b0 = *reinterpret_cast<const float4*>(&Bs[kk][tx * 4]);
            float4 b1 = *reinterpret_cast<const float4*>(&Bs[kk][tx * 4 + 64]);
            float a[8] = {a0.x, a0.y, a0.z, a0.w, a1.x, a1.y, a1.z, a1.w};
            float b[8] = {b0.x, b0.y, b0.z, b0.w, b1.x, b1.y, b1.z, b1.w};
#pragma unroll
            for (int i = 0; i < 8; ++i)
#pragma unroll
                for (int j = 0; j < 8; ++j)
                    acc[i][j] = fmaf(a[i], b[j], acc[i][j]);
        }
        __syncthreads();
    }

#pragma unroll
    for (int i = 0; i < 8; ++i) {
        int r = bm + ty * 4 + (i & 3) + ((i >> 2) * 64);
        if (r < M) {
            float4 v0 = make_float4(acc[i][0], acc[i][1], acc[i][2], acc[i][3]);
            float4 v1 = make_float4(acc[i][4], acc[i][5], acc[i][6], acc[i][7]);
            *reinterpret_cast<float4*>(&C[(size_t)r * ldc + bn + tx * 4])      = v0;
            *reinterpret_cast<float4*>(&C[(size_t)r * ldc + bn + 64 + tx * 4]) = v1;
        }
    }
}

__device__ __forceinline__ float softplus_f(float x)
{
    return fmaxf(x, 0.f) + log1pf(expf(-fabsf(x)));
}

// layer-1 aggregation + softplus: H1[i][f] = softplus(dinv[i]*(T1[i][f]*dinv[i] + sum dinv[s]*T1[s][f]))
__global__ __launch_bounds__(256) void agg1_kernel(const float* __restrict__ T1,
                                                   const float* __restrict__ dinv,
                                                   const int* __restrict__ rowptr,
                                                   const int* __restrict__ col,
                                                   float* __restrict__ H1, int N)
{
    int node = blockIdx.x;
    int f = threadIdx.x;                 // 0..255
    float di = dinv[node];
    float acc = T1[(size_t)node * 256 + f] * di;   // self loop (x di again at end)
    int beg = rowptr[node], end = rowptr[node + 1];

    __shared__ int   s_src[256];
    __shared__ float s_w[256];
    for (int base = beg; base < end; base += 256) {
        int cnt = min(256, end - base);
        if (f < cnt) {
            int s = col[base + f];
            s_src[f] = s;
            s_w[f]   = dinv[s];
        }
        __syncthreads();
        for (int j = 0; j < cnt; ++j) {
            acc = fmaf(s_w[j], T1[(size_t)s_src[j] * 256 + f], acc);
        }
        __syncthreads();
    }
    acc *= di;
    H1[(size_t)node * 256 + f] = softplus_f(acc);
}

// kappa column of GEMM2: T2k[i] = dot(H1[i,:], W1col). one wave per row.
__global__ __launch_bounds__(256) void kappa_col_kernel(const float* __restrict__ H1,
                                                        const float* __restrict__ W1col,
                                                        float* __restrict__ T2k, int N)
{
    __shared__ float w[256];
    int tid = threadIdx.x;
    w[tid] = W1col[tid];
    __syncthreads();
    int lane = tid & 63;
    int wid  = tid >> 6;
    int row  = blockIdx.x * 4 + wid;
    if (row >= N) return;
    float s = 0.f;
#pragma unroll
    for (int k = lane; k < 256; k += 64)
        s = fmaf(H1[(size_t)row * 256 + k], w[k], s);
#pragma unroll
    for (int off = 32; off > 0; off >>= 1)
        s += __shfl_down(s, off, 64);
    if (lane == 0) T2k[row] = s;
}

// layer-2 aggregation + softplus + Weibull epilogue, writes z, lbd, kappa.
__global__ __launch_bounds__(128) void agg2_kernel(const float* __restrict__ T2,
                                                   const float* __restrict__ T2k,
                                                   const float* __restrict__ dinv,
                                                   const int* __restrict__ rowptr,
                                                   const int* __restrict__ col,
                                                   float* __restrict__ z_out,
                                                   float* __restrict__ lbd_out,
                                                   float* __restrict__ kap_out, int N)
{
    int node = blockIdx.x;
    int f = threadIdx.x;                 // 0..127
    float di = dinv[node];
    float acc  = T2[(size_t)node * 128 + f] * di;
    float acck = (f == 0) ? T2k[node] * di : 0.f;
    int beg = rowptr[node], end = rowptr[node + 1];

    __shared__ int   s_src[128];
    __shared__ float s_w[128];
    __shared__ float s_g;
    for (int base = beg; base < end; base += 128) {
        int cnt = min(128, end - base);
        if (f < cnt) {
            int s = col[base + f];
            s_src[f] = s;
            s_w[f]   = dinv[s];
        }
        __syncthreads();
        for (int j = 0; j < cnt; ++j) {
            float wj = s_w[j];
            int   s  = s_src[j];
            acc = fmaf(wj, T2[(size_t)s * 128 + f], acc);
            if (f == 0) acck = fmaf(wj, T2k[s], acck);
        }
        __syncthreads();
    }
    acc  *= di;
    float sp = softplus_f(acc);
    if (f == 0) {
        acck *= di;
        float kv = softplus_f(acck) + 0.1f;
        kap_out[node] = kv;
        s_g = expf(lgammaf(1.0f + 1.0f / kv));
    }
    __syncthreads();
    float g = s_g;
    size_t o = (size_t)node * 128 + f;
    lbd_out[o] = sp;
    z_out[o]   = sp * g;
}

extern "C" void kernel_launch(void* const* d_in, const int* in_sizes, int n_in,
                              void* d_out, int out_size, void* d_ws, size_t ws_size,
                              hipStream_t stream)
{
    const float* x  = (const float*)d_in[0];
    const int*   ei = (const int*)d_in[1];
    const float* W0 = (const float*)d_in[2];
    const float* W1 = (const float*)d_in[3];

    const int N = in_sizes[0] / 512;      // 50000
    const int E = in_sizes[1] / 2;        // 1600000
    const int* src = ei;
    const int* dst = ei + E;

    char* w = (char*)d_ws;
    size_t off = 0;
    auto take = [&](size_t bytes) -> void* {
        void* p = (void*)(w + off);
        off = (off + bytes + 255) & ~(size_t)255;
        return p;
    };
    int*   cnt    = (int*)take((size_t)N * 4);
    int*   rowptr = (int*)take((size_t)(N + 1) * 4);
    int*   cursor = (int*)take((size_t)N * 4);
    float* dinv   = (float*)take((size_t)N * 4);
    int*   col    = (int*)take((size_t)E * 4);
    float* W1main = (float*)take((size_t)256 * 128 * 4);
    float* W1col  = (float*)take((size_t)256 * 4);
    float* T2k    = (float*)take((size_t)N * 4);
    float* H1     = (float*)take((size_t)N * 256 * 4);
    float* T1     = (float*)take((size_t)N * 256 * 4);
    float* T2     = T1;                   // T1 dead after agg1; reuse for T2

    float* z_out   = (float*)d_out;
    float* lbd_out = z_out + (size_t)N * 128;
    float* kap_out = lbd_out + (size_t)N * 128;

    hipMemsetAsync(cnt, 0, (size_t)N * 4, stream);
    count_kernel<<<(E + 255) / 256, 256, 0, stream>>>(dst, cnt, E);
    dinv_kernel<<<(N + 255) / 256, 256, 0, stream>>>(cnt, dinv, N);
    scan_kernel<<<1, 1024, 0, stream>>>(cnt, rowptr, cursor, N);
    scatter_kernel<<<(E + 255) / 256, 256, 0, stream>>>(src, dst, cursor, col, E);
    repack_w1<<<(256 * 129 + 255) / 256, 256, 0, stream>>>(W1, W1main, W1col);

    dim3 g1((N + BM - 1) / BM, 2);
    gemm_f32<<<g1, 256, 0, stream>>>(x, W0, T1, N, 256, 512, 512, 256, 256);
    agg1_kernel<<<N, 256, 0, stream>>>(T1, dinv, rowptr, col, H1, N);

    dim3 g2((N + BM - 1) / BM, 1);
    gemm_f32<<<g2, 256, 0, stream>>>(H1, W1main, T2, N, 128, 256, 256, 128, 128);
    kappa_col_kernel<<<(N + 3) / 4, 256, 0, stream>>>(H1, W1col, T2k, N);
    agg2_kernel<<<N, 128, 0, stream>>>(T2, T2k, dinv, rowptr, col, z_out, lbd_out, kap_out, N);
}

// Round 3
// 968.709 us; speedup vs baseline: 1.0528x; 1.0528x over previous
//
#include <hip/hip_runtime.h>
#include <hip/hip_bf16.h>
#include <math.h>

// ---------------------------------------------------------------------------
// InfNet: 2-layer GCN + Weibull epilogue, all-fp32 pipeline.
// Â = D^-1/2 (A + I) D^-1/2 applied as: out[i] = dinv[i]*(T[i]*dinv[i] + sum_e dinv[src]*T[src])
// R3: fix agg2 launch config (256 threads — kernel assumes 8 slots x 32 cols).
// ---------------------------------------------------------------------------

__global__ __launch_bounds__(256) void count_kernel(const int* __restrict__ dst,
                                                    int* __restrict__ cnt, int E)
{
    int e = blockIdx.x * blockDim.x + threadIdx.x;
    if (e < E) atomicAdd(&cnt[dst[e]], 1);
}

__global__ __launch_bounds__(256) void dinv_kernel(const int* __restrict__ cnt,
                                                   float* __restrict__ dinv, int N)
{
    int i = blockIdx.x * blockDim.x + threadIdx.x;
    if (i < N) dinv[i] = 1.0f / sqrtf((float)(cnt[i] + 1));   // +1 self-loop
}

// single-block exclusive scan, wave-shuffle based (3 barriers per 1024 chunk)
__global__ __launch_bounds__(1024) void scan_kernel(const int* __restrict__ cnt,
                                                    int* __restrict__ rowptr,
                                                    int* __restrict__ cursor, int N)
{
    __shared__ int wsum[16];
    int tid = threadIdx.x, lane = tid & 63, wid = tid >> 6;
    int carry = 0;
    for (int base = 0; base < N; base += 1024) {
        int i = base + tid;
        int v = (i < N) ? cnt[i] : 0;
        int s = v;
#pragma unroll
        for (int off = 1; off < 64; off <<= 1) {
            int t = __shfl_up(s, off, 64);
            if (lane >= off) s += t;
        }
        if (lane == 63) wsum[wid] = s;
        __syncthreads();
        if (tid < 16) {
            int w = wsum[tid];
#pragma unroll
            for (int off = 1; off < 16; off <<= 1) {
                int t = __shfl_up(w, off, 64);
                if (tid >= off) w += t;
            }
            wsum[tid] = w;
        }
        __syncthreads();
        int prev = (wid > 0) ? wsum[wid - 1] : 0;
        int excl = s - v + prev + carry;
        if (i < N) { rowptr[i] = excl; cursor[i] = excl; }
        carry += wsum[15];
        __syncthreads();          // protect wsum before next chunk
    }
    if (tid == 0) rowptr[N] = carry;
}

__global__ __launch_bounds__(256) void scatter_kernel(const int* __restrict__ src,
                                                      const int* __restrict__ dst,
                                                      int* __restrict__ cursor,
                                                      int* __restrict__ col, int E)
{
    int e = blockIdx.x * blockDim.x + threadIdx.x;
    if (e < E) {
        int d = dst[e];
        int pos = atomicAdd(&cursor[d], 1);
        col[pos] = src[e];
    }
}

// split W1 (256x129) into W1main (256x128) and W1col (256) so GEMM2 B-rows are
// 16B-aligned for float4 staging.
__global__ __launch_bounds__(256) void repack_w1(const float* __restrict__ W1,
                                                 float* __restrict__ W1main,
                                                 float* __restrict__ W1col)
{
    int i = blockIdx.x * blockDim.x + threadIdx.x;
    if (i < 256 * 129) {
        int k = i / 129, j = i % 129;
        float v = W1[i];
        if (j == 128) W1col[k] = v;
        else          W1main[k * 128 + j] = v;
    }
}

// fp32 tiled GEMM: C(MxN) = A(MxK) * B(KxN). BM=BN=128, BK=16, 256 thr, 8x8/thread.
#define BM 128
#define BN 128
#define BKK 16
__global__ __launch_bounds__(256) void gemm_f32(const float* __restrict__ A,
                                                const float* __restrict__ B,
                                                float* __restrict__ C,
                                                int M, int N, int K,
                                                int lda, int ldb, int ldc)
{
    __shared__ float As[BKK][BM + 4];
    __shared__ float Bs[BKK][BN + 8];

    int tid = threadIdx.x;
    int bm = blockIdx.x * BM;
    int bn = blockIdx.y * BN;
    int tx = tid & 15;
    int ty = tid >> 4;

    float acc[8][8];
#pragma unroll
    for (int i = 0; i < 8; ++i)
#pragma unroll
        for (int j = 0; j < 8; ++j) acc[i][j] = 0.f;

    int arow = tid >> 2;
    int akq  = (tid & 3) * 4;
    int bkr  = tid >> 5;
    int bcq  = (tid & 31) * 4;

    for (int k0 = 0; k0 < K; k0 += BKK) {
#pragma unroll
        for (int p = 0; p < 2; ++p) {
            int r  = arow + p * 64;
            int gr = bm + r;
            float4 v = make_float4(0.f, 0.f, 0.f, 0.f);
            if (gr < M) v = *reinterpret_cast<const float4*>(&A[(size_t)gr * lda + k0 + akq]);
            As[akq + 0][r] = v.x;
            As[akq + 1][r] = v.y;
            As[akq + 2][r] = v.z;
            As[akq + 3][r] = v.w;
        }
#pragma unroll
        for (int p = 0; p < 2; ++p) {
            int kr = bkr + p * 8;
            float4 v = *reinterpret_cast<const float4*>(&B[(size_t)(k0 + kr) * ldb + bn + bcq]);
            *reinterpret_cast<float4*>(&Bs[kr][bcq]) = v;
        }
        __syncthreads();
#pragma unroll
        for (int kk = 0; kk < BKK; ++kk) {
            float4 a0 = *reinterpret_cast<const float4*>(&As[kk][ty * 4]);
            float4 a1 = *reinterpret_cast<const float4*>(&As[kk][ty * 4 + 64]);
            float4 b0 = *reinterpret_cast<const float4*>(&Bs[kk][tx * 4]);
            float4 b1 = *reinterpret_cast<const float4*>(&Bs[kk][tx * 4 + 64]);
            float a[8] = {a0.x, a0.y, a0.z, a0.w, a1.x, a1.y, a1.z, a1.w};
            float b[8] = {b0.x, b0.y, b0.z, b0.w, b1.x, b1.y, b1.z, b1.w};
#pragma unroll
            for (int i = 0; i < 8; ++i)
#pragma unroll
                for (int j = 0; j < 8; ++j)
                    acc[i][j] = fmaf(a[i], b[j], acc[i][j]);
        }
        __syncthreads();
    }

#pragma unroll
    for (int i = 0; i < 8; ++i) {
        int r = bm + ty * 4 + (i & 3) + ((i >> 2) * 64);
        if (r < M) {
            float4 v0 = make_float4(acc[i][0], acc[i][1], acc[i][2], acc[i][3]);
            float4 v1 = make_float4(acc[i][4], acc[i][5], acc[i][6], acc[i][7]);
            *reinterpret_cast<float4*>(&C[(size_t)r * ldc + bn + tx * 4])      = v0;
            *reinterpret_cast<float4*>(&C[(size_t)r * ldc + bn + 64 + tx * 4]) = v1;
        }
    }
}

__device__ __forceinline__ float softplus_f(float x)
{
    return fmaxf(x, 0.f) + log1pf(expf(-fabsf(x)));
}

// layer-1 aggregation + softplus. 256 thr = 4 edge-slots (waves) x 64 float4 cols.
__global__ __launch_bounds__(256) void agg1_kernel(const float* __restrict__ T1,
                                                   const float* __restrict__ dinv,
                                                   const int* __restrict__ rowptr,
                                                   const int* __restrict__ col,
                                                   float* __restrict__ H1, int N)
{
    int node = blockIdx.x;
    int tid  = threadIdx.x;
    int c    = tid & 63;        // features 4c..4c+3
    int slot = tid >> 6;        // 0..3 == wave id
    float di = dinv[node];
    int beg = rowptr[node], end = rowptr[node + 1];

    float4 acc = make_float4(0.f, 0.f, 0.f, 0.f);
    __shared__ int    s_src[256];
    __shared__ float  s_w[256];
    __shared__ float4 red[4][64];

    for (int base = beg; base < end; base += 256) {
        int cnt = min(256, end - base);
        if (tid < cnt) {
            int s = col[base + tid];
            s_src[tid] = s;
            s_w[tid]   = dinv[s];
        }
        __syncthreads();
        for (int jb = 0; jb < cnt; jb += 4) {
            int j = jb + slot;           // wave-uniform
            if (j < cnt) {
                int   s = s_src[j];
                float w = s_w[j];
                float4 v = *reinterpret_cast<const float4*>(&T1[(size_t)s * 256 + c * 4]);
                acc.x = fmaf(w, v.x, acc.x);
                acc.y = fmaf(w, v.y, acc.y);
                acc.z = fmaf(w, v.z, acc.z);
                acc.w = fmaf(w, v.w, acc.w);
            }
        }
        __syncthreads();
    }

    red[slot][c] = acc;
    __syncthreads();
    if (slot == 0) {
        float4 a0 = red[0][c], a1 = red[1][c], a2 = red[2][c], a3 = red[3][c];
        float4 self = *reinterpret_cast<const float4*>(&T1[(size_t)node * 256 + c * 4]);
        float4 o;
        o.x = softplus_f((a0.x + a1.x + a2.x + a3.x + self.x * di) * di);
        o.y = softplus_f((a0.y + a1.y + a2.y + a3.y + self.y * di) * di);
        o.z = softplus_f((a0.z + a1.z + a2.z + a3.z + self.z * di) * di);
        o.w = softplus_f((a0.w + a1.w + a2.w + a3.w + self.w * di) * di);
        *reinterpret_cast<float4*>(&H1[(size_t)node * 256 + c * 4]) = o;
    }
}

// kappa column of GEMM2: T2k[i] = dot(H1[i,:], W1col). one wave per row.
__global__ __launch_bounds__(256) void kappa_col_kernel(const float* __restrict__ H1,
                                                        const float* __restrict__ W1col,
                                                        float* __restrict__ T2k, int N)
{
    __shared__ float w[256];
    int tid = threadIdx.x;
    w[tid] = W1col[tid];
    __syncthreads();
    int lane = tid & 63;
    int wid  = tid >> 6;
    int row  = blockIdx.x * 4 + wid;
    if (row >= N) return;
    float s = 0.f;
#pragma unroll
    for (int k = lane; k < 256; k += 64)
        s = fmaf(H1[(size_t)row * 256 + k], w[k], s);
#pragma unroll
    for (int off = 32; off > 0; off >>= 1)
        s += __shfl_down(s, off, 64);
    if (lane == 0) T2k[row] = s;
}

// layer-2 aggregation + softplus + Weibull epilogue.
// 256 thr = 8 edge-slots x 32 float4 cols (128 features).
__global__ __launch_bounds__(256) void agg2_kernel(const float* __restrict__ T2,
                                                   const float* __restrict__ T2k,
                                                   const float* __restrict__ dinv,
                                                   const int* __restrict__ rowptr,
                                                   const int* __restrict__ col,
                                                   float* __restrict__ z_out,
                                                   float* __restrict__ lbd_out,
                                                   float* __restrict__ kap_out, int N)
{
    int node = blockIdx.x;
    int tid  = threadIdx.x;
    int c    = tid & 31;        // features 4c..4c+3
    int slot = tid >> 5;        // 0..7
    float di = dinv[node];
    int beg = rowptr[node], end = rowptr[node + 1];

    float4 acc  = make_float4(0.f, 0.f, 0.f, 0.f);
    float  acck = 0.f;          // kappa pre-activation, edge part
    __shared__ int    s_src[256];
    __shared__ float  s_w[256];
    __shared__ float4 red[8][32];
    __shared__ float  s_kred[4];
    __shared__ float  s_g;

    for (int base = beg; base < end; base += 256) {
        int cnt = min(256, end - base);
        if (tid < cnt) {
            int s = col[base + tid];
            float w = dinv[s];
            s_src[tid] = s;
            s_w[tid]   = w;
            acck = fmaf(w, T2k[s], acck);   // parallel kappa gather
        }
        __syncthreads();
        for (int jb = 0; jb < cnt; jb += 8) {
            int j = jb + slot;
            if (j < cnt) {
                int   s = s_src[j];
                float w = s_w[j];
                float4 v = *reinterpret_cast<const float4*>(&T2[(size_t)s * 128 + c * 4]);
                acc.x = fmaf(w, v.x, acc.x);
                acc.y = fmaf(w, v.y, acc.y);
                acc.z = fmaf(w, v.z, acc.z);
                acc.w = fmaf(w, v.w, acc.w);
            }
        }
        __syncthreads();
    }

    // block-reduce acck (sum over all 256 threads)
#pragma unroll
    for (int off = 32; off > 0; off >>= 1)
        acck += __shfl_down(acck, off, 64);
    if ((tid & 63) == 0) s_kred[tid >> 6] = acck;

    red[slot][c] = acc;
    __syncthreads();

    if (tid == 0) {
        float ak = (s_kred[0] + s_kred[1] + s_kred[2] + s_kred[3] + T2k[node] * di) * di;
        float kv = softplus_f(ak) + 0.1f;
        s_g  = expf(lgammaf(1.0f + 1.0f / kv));
        kap_out[node] = kv;
    }
    __syncthreads();

    if (slot == 0) {
        float4 a = red[0][c];
#pragma unroll
        for (int p = 1; p < 8; ++p) {
            float4 b = red[p][c];
            a.x += b.x; a.y += b.y; a.z += b.z; a.w += b.w;
        }
        float4 self = *reinterpret_cast<const float4*>(&T2[(size_t)node * 128 + c * 4]);
        float4 sp;
        sp.x = softplus_f((a.x + self.x * di) * di);
        sp.y = softplus_f((a.y + self.y * di) * di);
        sp.z = softplus_f((a.z + self.z * di) * di);
        sp.w = softplus_f((a.w + self.w * di) * di);
        float g = s_g;
        size_t o = (size_t)node * 128 + c * 4;
        *reinterpret_cast<float4*>(&lbd_out[o]) = sp;
        float4 zv = make_float4(sp.x * g, sp.y * g, sp.z * g, sp.w * g);
        *reinterpret_cast<float4*>(&z_out[o]) = zv;
    }
}

extern "C" void kernel_launch(void* const* d_in, const int* in_sizes, int n_in,
                              void* d_out, int out_size, void* d_ws, size_t ws_size,
                              hipStream_t stream)
{
    const float* x  = (const float*)d_in[0];
    const int*   ei = (const int*)d_in[1];
    const float* W0 = (const float*)d_in[2];
    const float* W1 = (const float*)d_in[3];

    const int N = in_sizes[0] / 512;      // 50000
    const int E = in_sizes[1] / 2;        // 1600000
    const int* src = ei;
    const int* dst = ei + E;

    char* w = (char*)d_ws;
    size_t off = 0;
    auto take = [&](size_t bytes) -> void* {
        void* p = (void*)(w + off);
        off = (off + bytes + 255) & ~(size_t)255;
        return p;
    };
    int*   cnt    = (int*)take((size_t)N * 4);
    int*   rowptr = (int*)take((size_t)(N + 1) * 4);
    int*   cursor = (int*)take((size_t)N * 4);
    float* dinv   = (float*)take((size_t)N * 4);
    int*   col    = (int*)take((size_t)E * 4);
    float* W1main = (float*)take((size_t)256 * 128 * 4);
    float* W1col  = (float*)take((size_t)256 * 4);
    float* T2k    = (float*)take((size_t)N * 4);
    float* H1     = (float*)take((size_t)N * 256 * 4);
    float* T1     = (float*)take((size_t)N * 256 * 4);
    float* T2     = T1;                   // T1 dead after agg1; reuse for T2

    float* z_out   = (float*)d_out;
    float* lbd_out = z_out + (size_t)N * 128;
    float* kap_out = lbd_out + (size_t)N * 128;

    hipMemsetAsync(cnt, 0, (size_t)N * 4, stream);
    count_kernel<<<(E + 255) / 256, 256, 0, stream>>>(dst, cnt, E);
    dinv_kernel<<<(N + 255) / 256, 256, 0, stream>>>(cnt, dinv, N);
    scan_kernel<<<1, 1024, 0, stream>>>(cnt, rowptr, cursor, N);
    scatter_kernel<<<(E + 255) / 256, 256, 0, stream>>>(src, dst, cursor, col, E);
    repack_w1<<<(256 * 129 + 255) / 256, 256, 0, stream>>>(W1, W1main, W1col);

    dim3 g1((N + BM - 1) / BM, 2);
    gemm_f32<<<g1, 256, 0, stream>>>(x, W0, T1, N, 256, 512, 512, 256, 256);
    agg1_kernel<<<N, 256, 0, stream>>>(T1, dinv, rowptr, col, H1, N);

    dim3 g2((N + BM - 1) / BM, 1);
    gemm_f32<<<g2, 256, 0, stream>>>(H1, W1main, T2, N, 128, 256, 256, 128, 128);
    kappa_col_kernel<<<(N + 3) / 4, 256, 0, stream>>>(H1, W1col, T2k, N);
    agg2_kernel<<<N, 256, 0, stream>>>(T2, T2k, dinv, rowptr, col, z_out, lbd_out, kap_out, N);
}

// Round 4
// 918.052 us; speedup vs baseline: 1.1109x; 1.0552x over previous
//
#include <hip/hip_runtime.h>
#include <hip/hip_bf16.h>
#include <math.h>

// ---------------------------------------------------------------------------
// InfNet: 2-layer GCN + Weibull epilogue.
// GEMMs: bf16x3 split (Ah*Bh + Al*Bh + Ah*Bl) via MFMA 16x16x32, fp32 acc.
// Aggregations stay fp32 (kappa-path error amplification ~2e4 forbids bf16 gather).
// ---------------------------------------------------------------------------

typedef unsigned short ushort_t;
typedef __attribute__((ext_vector_type(8))) short bf16x8;
typedef __attribute__((ext_vector_type(4))) float f32x4;

__device__ __forceinline__ ushort_t f2bf(float f) {
    union { float f; unsigned u; } x; x.f = f;
    unsigned r = x.u + 0x7FFF + ((x.u >> 16) & 1);   // RNE
    return (ushort_t)(r >> 16);
}
__device__ __forceinline__ float bf2f(ushort_t s) {
    union { unsigned u; float f; } x; x.u = ((unsigned)s) << 16; return x.f;
}

__device__ __forceinline__ void async_copy16(const void* gsrc, void* ldst) {
    __builtin_amdgcn_global_load_lds(
        (const __attribute__((address_space(1))) unsigned int*)gsrc,
        (__attribute__((address_space(3))) unsigned int*)ldst,
        16, 0, 0);
}

// ---------------- graph preprocessing ----------------

__global__ __launch_bounds__(256) void count_kernel(const int* __restrict__ dst,
                                                    int* __restrict__ cnt, int E)
{
    int e = blockIdx.x * blockDim.x + threadIdx.x;
    if (e < E) atomicAdd(&cnt[dst[e]], 1);
}

// per-chunk scan: rowptr[i] = exclusive scan within chunk; blksum[b] = chunk total.
// also dinv[i] = rsqrt(cnt+1).
__global__ __launch_bounds__(1024) void scan_local(const int* __restrict__ cnt,
                                                   int* __restrict__ rowptr,
                                                   float* __restrict__ dinv,
                                                   int* __restrict__ blksum, int N)
{
    __shared__ int wsum[16];
    int tid = threadIdx.x, lane = tid & 63, wid = tid >> 6;
    int i = blockIdx.x * 1024 + tid;
    int v = (i < N) ? cnt[i] : 0;
    if (i < N) dinv[i] = rsqrtf((float)(v + 1));
    int s = v;
#pragma unroll
    for (int off = 1; off < 64; off <<= 1) {
        int t = __shfl_up(s, off, 64);
        if (lane >= off) s += t;
    }
    if (lane == 63) wsum[wid] = s;
    __syncthreads();
    if (tid < 16) {
        int w = wsum[tid];
#pragma unroll
        for (int off = 1; off < 16; off <<= 1) {
            int t = __shfl_up(w, off, 64);
            if (tid >= off) w += t;
        }
        wsum[tid] = w;
    }
    __syncthreads();
    int excl = s - v + (wid ? wsum[wid - 1] : 0);
    if (i < N) rowptr[i] = excl;
    if (tid == 0) blksum[blockIdx.x] = wsum[15];
}

// exclusive scan of <=64 block sums (single wave), writes rowptr[N]=total.
__global__ __launch_bounds__(64) void scan_blk(const int* __restrict__ blksum,
                                               int* __restrict__ blkoff,
                                               int nblk, int* __restrict__ rowptr, int N)
{
    int tid = threadIdx.x;
    int v = (tid < nblk) ? blksum[tid] : 0;
    int s = v;
#pragma unroll
    for (int off = 1; off < 64; off <<= 1) {
        int t = __shfl_up(s, off, 64);
        if (tid >= off) s += t;
    }
    if (tid < nblk) blkoff[tid] = s - v;
    if (tid == nblk - 1) rowptr[N] = s;
}

__global__ __launch_bounds__(256) void scan_add(int* __restrict__ rowptr,
                                                int* __restrict__ cursor,
                                                const int* __restrict__ blkoff, int N)
{
    int i = blockIdx.x * blockDim.x + threadIdx.x;
    if (i < N) {
        int r = rowptr[i] + blkoff[i >> 10];
        rowptr[i] = r;
        cursor[i] = r;
    }
}

__global__ __launch_bounds__(256) void scatter_kernel(const int* __restrict__ src,
                                                      const int* __restrict__ dst,
                                                      int* __restrict__ cursor,
                                                      int* __restrict__ col, int E)
{
    int e = blockIdx.x * blockDim.x + threadIdx.x;
    if (e < E) {
        int d = dst[e];
        int pos = atomicAdd(&cursor[d], 1);
        col[pos] = src[e];
    }
}

// ---------------- operand conversion (bf16 hi/lo split) ----------------

// Abig (M_pad x 1024): cols [0,512)=hi(x), [512,1024)=lo(x). Pad rows zeroed.
__global__ __launch_bounds__(256) void conv_x(const float* __restrict__ x,
                                              ushort_t* __restrict__ Abig,
                                              int M, int M_pad)
{
    int id = blockIdx.x * blockDim.x + threadIdx.x;     // M_pad*128 threads
    int r = id >> 7, q = id & 127;
    if (r >= M_pad) return;
    float4 v = make_float4(0.f, 0.f, 0.f, 0.f);
    if (r < M) v = *reinterpret_cast<const float4*>(&x[(size_t)r * 512 + q * 4]);
    ushort4 h, l;
    h.x = f2bf(v.x); l.x = f2bf(v.x - bf2f(h.x));
    h.y = f2bf(v.y); l.y = f2bf(v.y - bf2f(h.y));
    h.z = f2bf(v.z); l.z = f2bf(v.z - bf2f(h.z));
    h.w = f2bf(v.w); l.w = f2bf(v.w - bf2f(h.w));
    ushort_t* rowp = Abig + (size_t)r * 1024;
    *reinterpret_cast<ushort4*>(rowp + q * 4)       = h;
    *reinterpret_cast<ushort4*>(rowp + 512 + q * 4) = l;
}

// W0bigT (256 x 1536), row n: [0,512)=hi(W0[:,n]), [512,1024)=hi again, [1024,1536)=lo.
__global__ __launch_bounds__(256) void conv_w0(const float* __restrict__ W0,
                                               ushort_t* __restrict__ BT)
{
    int id = blockIdx.x * blockDim.x + threadIdx.x;     // 256*512
    int k = id & 511, n = id >> 9;
    if (n >= 256) return;
    float v = W0[(size_t)k * 256 + n];
    ushort_t h = f2bf(v);
    ushort_t l = f2bf(v - bf2f(h));
    ushort_t* rowp = BT + (size_t)n * 1536;
    rowp[k] = h; rowp[512 + k] = h; rowp[1024 + k] = l;
}

// W1bigT (128 x 768), row n: [0,256)=hi(W1[:,n]), [256,512)=hi, [512,768)=lo.
// Also extracts W1col (kappa column, fp32).
__global__ __launch_bounds__(256) void conv_w1(const float* __restrict__ W1,
                                               ushort_t* __restrict__ BT,
                                               float* __restrict__ W1col)
{
    int id = blockIdx.x * blockDim.x + threadIdx.x;     // 128*256
    int k = id & 255, n = id >> 8;
    if (n >= 128) return;
    float v = W1[(size_t)k * 129 + n];
    ushort_t h = f2bf(v);
    ushort_t l = f2bf(v - bf2f(h));
    ushort_t* rowp = BT + (size_t)n * 768;
    rowp[k] = h; rowp[256 + k] = h; rowp[512 + k] = l;
    if (n == 0) W1col[k] = W1[(size_t)k * 129 + 128];
}

// ---------------- MFMA GEMM: C(MxN) = A(MxK_bf16) * BT(NxK_bf16)^T ----------------
// 128x128 block tile, BK=32, 256 thr = 4 waves (2x2 of 64x64), 16x16x32 MFMA.
__global__ __launch_bounds__(256) void gemm_bf16(const ushort_t* __restrict__ A, int lda,
                                                 const ushort_t* __restrict__ BT, int ldbt,
                                                 float* __restrict__ C, int ldc,
                                                 int M, int K, int beta)
{
    __shared__ short As[128 * 32];   // row-major [128][32] bf16
    __shared__ short Bs[128 * 32];   // BT tile, row-major [128][32]

    int tid  = threadIdx.x;
    int w    = tid >> 6;
    int lane = tid & 63;
    int lm   = lane & 15;
    int lq   = lane >> 4;            // 0..3
    int bm   = blockIdx.x * 128;
    int bn   = blockIdx.y * 128;
    int wr   = (w >> 1) * 64;
    int wc   = (w & 1) * 64;

    f32x4 acc[4][4];
#pragma unroll
    for (int i = 0; i < 4; ++i)
#pragma unroll
        for (int j = 0; j < 4; ++j) acc[i][j] = (f32x4)(0.f);

    int srow = (lane >> 2);          // 0..15
    int scol = (lane & 3) * 16;      // byte offset within 64B row

    for (int k0 = 0; k0 < K; k0 += 32) {
#pragma unroll
        for (int q = 0; q < 2; ++q) {
            int r = w * 32 + q * 16 + srow;
            const char* ga = (const char*)A + ((size_t)(bm + r) * lda + k0) * 2 + scol;
            async_copy16(ga, (char*)As + (size_t)(w * 32 + q * 16) * 64);
        }
#pragma unroll
        for (int q = 0; q < 2; ++q) {
            int r = w * 32 + q * 16 + srow;
            const char* gb = (const char*)BT + ((size_t)(bn + r) * ldbt + k0) * 2 + scol;
            async_copy16(gb, (char*)Bs + (size_t)(w * 32 + q * 16) * 64);
        }
        __syncthreads();

        bf16x8 afr[4], bfr[4];
#pragma unroll
        for (int mi = 0; mi < 4; ++mi)
            afr[mi] = *reinterpret_cast<const bf16x8*>(&As[(wr + mi * 16 + lm) * 32 + lq * 8]);
#pragma unroll
        for (int ni = 0; ni < 4; ++ni)
            bfr[ni] = *reinterpret_cast<const bf16x8*>(&Bs[(wc + ni * 16 + lm) * 32 + lq * 8]);
#pragma unroll
        for (int mi = 0; mi < 4; ++mi)
#pragma unroll
            for (int ni = 0; ni < 4; ++ni)
                acc[mi][ni] = __builtin_amdgcn_mfma_f32_16x16x32_bf16(
                    afr[mi], bfr[ni], acc[mi][ni], 0, 0, 0);
        __syncthreads();
    }

#pragma unroll
    for (int mi = 0; mi < 4; ++mi) {
#pragma unroll
        for (int ni = 0; ni < 4; ++ni) {
            int rbase = bm + wr + mi * 16 + lq * 4;
            int cc    = bn + wc + ni * 16 + lm;
#pragma unroll
            for (int e = 0; e < 4; ++e) {
                int r = rbase + e;
                if (r < M) {
                    float v = acc[mi][ni][e];
                    if (beta) C[(size_t)r * ldc + cc] += v;
                    else      C[(size_t)r * ldc + cc]  = v;
                }
            }
        }
    }
}

// ---------------- fused pieces ----------------

__device__ __forceinline__ float softplus_f(float x)
{
    return fmaxf(x, 0.f) + log1pf(expf(-fabsf(x)));
}

// layer-1 aggregation + softplus -> H1big bf16 [hi(256) | lo(256)] per node.
__global__ __launch_bounds__(256) void agg1_kernel(const float* __restrict__ T1,
                                                   const float* __restrict__ dinv,
                                                   const int* __restrict__ rowptr,
                                                   const int* __restrict__ col,
                                                   ushort_t* __restrict__ H1big, int N)
{
    int node = blockIdx.x;
    int tid  = threadIdx.x;
    int c    = tid & 63;        // features 4c..4c+3
    int slot = tid >> 6;        // 0..3 == wave id
    float di = dinv[node];
    int beg = rowptr[node], end = rowptr[node + 1];

    float4 acc = make_float4(0.f, 0.f, 0.f, 0.f);
    __shared__ int    s_src[256];
    __shared__ float  s_w[256];
    __shared__ float4 red[4][64];

    for (int base = beg; base < end; base += 256) {
        int cnt = min(256, end - base);
        if (tid < cnt) {
            int s = col[base + tid];
            s_src[tid] = s;
            s_w[tid]   = dinv[s];
        }
        __syncthreads();
        for (int jb = 0; jb < cnt; jb += 4) {
            int j = jb + slot;
            if (j < cnt) {
                int   s = s_src[j];
                float w = s_w[j];
                float4 v = *reinterpret_cast<const float4*>(&T1[(size_t)s * 256 + c * 4]);
                acc.x = fmaf(w, v.x, acc.x);
                acc.y = fmaf(w, v.y, acc.y);
                acc.z = fmaf(w, v.z, acc.z);
                acc.w = fmaf(w, v.w, acc.w);
            }
        }
        __syncthreads();
    }

    red[slot][c] = acc;
    __syncthreads();
    if (slot == 0) {
        float4 a0 = red[0][c], a1 = red[1][c], a2 = red[2][c], a3 = red[3][c];
        float4 self = *reinterpret_cast<const float4*>(&T1[(size_t)node * 256 + c * 4]);
        float4 o;
        o.x = softplus_f((a0.x + a1.x + a2.x + a3.x + self.x * di) * di);
        o.y = softplus_f((a0.y + a1.y + a2.y + a3.y + self.y * di) * di);
        o.z = softplus_f((a0.z + a1.z + a2.z + a3.z + self.z * di) * di);
        o.w = softplus_f((a0.w + a1.w + a2.w + a3.w + self.w * di) * di);
        ushort4 h, l;
        h.x = f2bf(o.x); l.x = f2bf(o.x - bf2f(h.x));
        h.y = f2bf(o.y); l.y = f2bf(o.y - bf2f(h.y));
        h.z = f2bf(o.z); l.z = f2bf(o.z - bf2f(h.z));
        h.w = f2bf(o.w); l.w = f2bf(o.w - bf2f(h.w));
        ushort_t* rowp = H1big + (size_t)node * 512;
        *reinterpret_cast<ushort4*>(rowp + c * 4)       = h;
        *reinterpret_cast<ushort4*>(rowp + 256 + c * 4) = l;
    }
}

// kappa column: T2k[i] = dot(H1[i,:], W1col), H1 reconstructed hi+lo.
__global__ __launch_bounds__(256) void kappa_col_kernel(const ushort_t* __restrict__ H1big,
                                                        const float* __restrict__ W1col,
                                                        float* __restrict__ T2k, int N)
{
    __shared__ float w[256];
    int tid = threadIdx.x;
    w[tid] = W1col[tid];
    __syncthreads();
    int lane = tid & 63;
    int wid  = tid >> 6;
    int row  = blockIdx.x * 4 + wid;
    if (row >= N) return;
    const ushort_t* rowp = H1big + (size_t)row * 512;
    float s = 0.f;
#pragma unroll
    for (int k = lane; k < 256; k += 64) {
        float hv = bf2f(rowp[k]) + bf2f(rowp[256 + k]);
        s = fmaf(hv, w[k], s);
    }
#pragma unroll
    for (int off = 32; off > 0; off >>= 1)
        s += __shfl_down(s, off, 64);
    if (lane == 0) T2k[row] = s;
}

// layer-2 aggregation + softplus + Weibull epilogue.
__global__ __launch_bounds__(256) void agg2_kernel(const float* __restrict__ T2,
                                                   const float* __restrict__ T2k,
                                                   const float* __restrict__ dinv,
                                                   const int* __restrict__ rowptr,
                                                   const int* __restrict__ col,
                                                   float* __restrict__ z_out,
                                                   float* __restrict__ lbd_out,
                                                   float* __restrict__ kap_out, int N)
{
    int node = blockIdx.x;
    int tid  = threadIdx.x;
    int c    = tid & 31;
    int slot = tid >> 5;        // 0..7
    float di = dinv[node];
    int beg = rowptr[node], end = rowptr[node + 1];

    float4 acc  = make_float4(0.f, 0.f, 0.f, 0.f);
    float  acck = 0.f;
    __shared__ int    s_src[256];
    __shared__ float  s_w[256];
    __shared__ float4 red[8][32];
    __shared__ float  s_kred[4];
    __shared__ float  s_g;

    for (int base = beg; base < end; base += 256) {
        int cnt = min(256, end - base);
        if (tid < cnt) {
            int s = col[base + tid];
            float w = dinv[s];
            s_src[tid] = s;
            s_w[tid]   = w;
            acck = fmaf(w, T2k[s], acck);
        }
        __syncthreads();
        for (int jb = 0; jb < cnt; jb += 8) {
            int j = jb + slot;
            if (j < cnt) {
                int   s = s_src[j];
                float w = s_w[j];
                float4 v = *reinterpret_cast<const float4*>(&T2[(size_t)s * 128 + c * 4]);
                acc.x = fmaf(w, v.x, acc.x);
                acc.y = fmaf(w, v.y, acc.y);
                acc.z = fmaf(w, v.z, acc.z);
                acc.w = fmaf(w, v.w, acc.w);
            }
        }
        __syncthreads();
    }

#pragma unroll
    for (int off = 32; off > 0; off >>= 1)
        acck += __shfl_down(acck, off, 64);
    if ((tid & 63) == 0) s_kred[tid >> 6] = acck;

    red[slot][c] = acc;
    __syncthreads();

    if (tid == 0) {
        float ak = (s_kred[0] + s_kred[1] + s_kred[2] + s_kred[3] + T2k[node] * di) * di;
        float kv = softplus_f(ak) + 0.1f;
        s_g = expf(lgammaf(1.0f + 1.0f / kv));
        kap_out[node] = kv;
    }
    __syncthreads();

    if (slot == 0) {
        float4 a = red[0][c];
#pragma unroll
        for (int p = 1; p < 8; ++p) {
            float4 b = red[p][c];
            a.x += b.x; a.y += b.y; a.z += b.z; a.w += b.w;
        }
        float4 self = *reinterpret_cast<const float4*>(&T2[(size_t)node * 128 + c * 4]);
        float4 sp;
        sp.x = softplus_f((a.x + self.x * di) * di);
        sp.y = softplus_f((a.y + self.y * di) * di);
        sp.z = softplus_f((a.z + self.z * di) * di);
        sp.w = softplus_f((a.w + self.w * di) * di);
        float g = s_g;
        size_t o = (size_t)node * 128 + c * 4;
        *reinterpret_cast<float4*>(&lbd_out[o]) = sp;
        float4 zv = make_float4(sp.x * g, sp.y * g, sp.z * g, sp.w * g);
        *reinterpret_cast<float4*>(&z_out[o]) = zv;
    }
}

extern "C" void kernel_launch(void* const* d_in, const int* in_sizes, int n_in,
                              void* d_out, int out_size, void* d_ws, size_t ws_size,
                              hipStream_t stream)
{
    const float* x  = (const float*)d_in[0];
    const int*   ei = (const int*)d_in[1];
    const float* W0 = (const float*)d_in[2];
    const float* W1 = (const float*)d_in[3];

    const int N = in_sizes[0] / 512;      // 50000
    const int E = in_sizes[1] / 2;        // 1600000
    const int* src = ei;
    const int* dst = ei + E;

    const int mblocks = (N + 127) / 128;  // 391
    const int M_pad   = mblocks * 128;    // 50048
    const int nchunk  = (N + 1023) / 1024; // 49

    char* w = (char*)d_ws;
    size_t off = 0;
    auto take = [&](size_t bytes) -> void* {
        void* p = (void*)(w + off);
        off = (off + bytes + 255) & ~(size_t)255;
        return p;
    };
    int*      cnt    = (int*)take((size_t)N * 4);
    int*      rowptr = (int*)take((size_t)(N + 1) * 4);
    int*      cursor = (int*)take((size_t)N * 4);
    float*    dinv   = (float*)take((size_t)N * 4);
    int*      col    = (int*)take((size_t)E * 4);
    int*      blksum = (int*)take(64 * 4);
    int*      blkoff = (int*)take(64 * 4);
    ushort_t* W0bigT = (ushort_t*)take((size_t)256 * 1536 * 2);
    ushort_t* W1bigT = (ushort_t*)take((size_t)128 * 768 * 2);
    float*    W1col  = (float*)take((size_t)256 * 4);
    float*    T2k    = (float*)take((size_t)N * 4);
    float*    T1     = (float*)take((size_t)N * 256 * 4);
    float*    T2     = T1;                 // T1 dead after agg1; reuse
    ushort_t* Abig   = (ushort_t*)take((size_t)M_pad * 1024 * 2);   // 102.5 MB
    ushort_t* H1big  = Abig;               // alias: Abig dead after gemm1

    float* z_out   = (float*)d_out;
    float* lbd_out = z_out + (size_t)N * 128;
    float* kap_out = lbd_out + (size_t)N * 128;

    hipMemsetAsync(cnt, 0, (size_t)N * 4, stream);
    count_kernel<<<(E + 255) / 256, 256, 0, stream>>>(dst, cnt, E);
    scan_local<<<nchunk, 1024, 0, stream>>>(cnt, rowptr, dinv, blksum, N);
    scan_blk<<<1, 64, 0, stream>>>(blksum, blkoff, nchunk, rowptr, N);
    scan_add<<<(N + 255) / 256, 256, 0, stream>>>(rowptr, cursor, blkoff, N);
    scatter_kernel<<<(E + 255) / 256, 256, 0, stream>>>(src, dst, cursor, col, E);

    conv_x<<<(M_pad * 128) / 256, 256, 0, stream>>>(x, Abig, N, M_pad);
    conv_w0<<<(256 * 512) / 256, 256, 0, stream>>>(W0, W0bigT);
    conv_w1<<<(128 * 256) / 256, 256, 0, stream>>>(W1, W1bigT, W1col);

    // GEMM1: T1 = x @ W0  (bf16x3 split). c1: [Ah|Al]*[Bh;Bh]; c2: Ah*Bl.
    dim3 g1(mblocks, 2);
    gemm_bf16<<<g1, 256, 0, stream>>>(Abig, 1024, W0bigT,        1536, T1, 256, N, 1024, 0);
    gemm_bf16<<<g1, 256, 0, stream>>>(Abig, 1024, W0bigT + 1024, 1536, T1, 256, N,  512, 1);

    agg1_kernel<<<N, 256, 0, stream>>>(T1, dinv, rowptr, col, H1big, N);

    // GEMM2: T2 = H1 @ W1main (bf16x3 split).
    dim3 g2(mblocks, 1);
    gemm_bf16<<<g2, 256, 0, stream>>>(H1big, 512, W1bigT,       768, T2, 128, N, 512, 0);
    gemm_bf16<<<g2, 256, 0, stream>>>(H1big, 512, W1bigT + 512, 768, T2, 128, N, 256, 1);

    kappa_col_kernel<<<(N + 3) / 4, 256, 0, stream>>>(H1big, W1col, T2k, N);
    agg2_kernel<<<N, 256, 0, stream>>>(T2, T2k, dinv, rowptr, col, z_out, lbd_out, kap_out, N);
}

// Round 5
// 852.594 us; speedup vs baseline: 1.1962x; 1.0768x over previous
//
#include <hip/hip_runtime.h>
#include <hip/hip_bf16.h>
#include <math.h>

// ---------------------------------------------------------------------------
// InfNet: 2-layer GCN + Weibull epilogue.
// GEMMs: bf16x3 split as ONE pass: [Ah|Al|Ah] * [Bh;Bh;Bl] via K-wrap remap.
// Aggregations fp32 (kappa-path error amplification forbids bf16 gathers),
// 4x-unrolled gathers for memory-level parallelism.
// ---------------------------------------------------------------------------

typedef unsigned short ushort_t;
typedef __attribute__((ext_vector_type(8))) short bf16x8;
typedef __attribute__((ext_vector_type(4))) float f32x4;

__device__ __forceinline__ ushort_t f2bf(float f) {
    union { float f; unsigned u; } x; x.f = f;
    unsigned r = x.u + 0x7FFF + ((x.u >> 16) & 1);   // RNE
    return (ushort_t)(r >> 16);
}
__device__ __forceinline__ float bf2f(ushort_t s) {
    union { unsigned u; float f; } x; x.u = ((unsigned)s) << 16; return x.f;
}

__device__ __forceinline__ void async_copy16(const void* gsrc, void* ldst) {
    __builtin_amdgcn_global_load_lds(
        (const __attribute__((address_space(1))) unsigned int*)gsrc,
        (__attribute__((address_space(3))) unsigned int*)ldst,
        16, 0, 0);
}

// ---------------- graph preprocessing ----------------

__global__ __launch_bounds__(256) void count_kernel(const int* __restrict__ dst,
                                                    int* __restrict__ cnt, int E)
{
    int e = blockIdx.x * blockDim.x + threadIdx.x;
    if (e < E) atomicAdd(&cnt[dst[e]], 1);
}

__global__ __launch_bounds__(1024) void scan_local(const int* __restrict__ cnt,
                                                   int* __restrict__ rowptr,
                                                   float* __restrict__ dinv,
                                                   int* __restrict__ blksum, int N)
{
    __shared__ int wsum[16];
    int tid = threadIdx.x, lane = tid & 63, wid = tid >> 6;
    int i = blockIdx.x * 1024 + tid;
    int v = (i < N) ? cnt[i] : 0;
    if (i < N) dinv[i] = rsqrtf((float)(v + 1));
    int s = v;
#pragma unroll
    for (int off = 1; off < 64; off <<= 1) {
        int t = __shfl_up(s, off, 64);
        if (lane >= off) s += t;
    }
    if (lane == 63) wsum[wid] = s;
    __syncthreads();
    if (tid < 16) {
        int w = wsum[tid];
#pragma unroll
        for (int off = 1; off < 16; off <<= 1) {
            int t = __shfl_up(w, off, 64);
            if (tid >= off) w += t;
        }
        wsum[tid] = w;
    }
    __syncthreads();
    int excl = s - v + (wid ? wsum[wid - 1] : 0);
    if (i < N) rowptr[i] = excl;
    if (tid == 0) blksum[blockIdx.x] = wsum[15];
}

__global__ __launch_bounds__(64) void scan_blk(const int* __restrict__ blksum,
                                               int* __restrict__ blkoff,
                                               int nblk, int* __restrict__ rowptr, int N)
{
    int tid = threadIdx.x;
    int v = (tid < nblk) ? blksum[tid] : 0;
    int s = v;
#pragma unroll
    for (int off = 1; off < 64; off <<= 1) {
        int t = __shfl_up(s, off, 64);
        if (tid >= off) s += t;
    }
    if (tid < nblk) blkoff[tid] = s - v;
    if (tid == nblk - 1) rowptr[N] = s;
}

__global__ __launch_bounds__(256) void scan_add(int* __restrict__ rowptr,
                                                int* __restrict__ cursor,
                                                const int* __restrict__ blkoff, int N)
{
    int i = blockIdx.x * blockDim.x + threadIdx.x;
    if (i < N) {
        int r = rowptr[i] + blkoff[i >> 10];
        rowptr[i] = r;
        cursor[i] = r;
    }
}

__global__ __launch_bounds__(256) void scatter_kernel(const int* __restrict__ src,
                                                      const int* __restrict__ dst,
                                                      int* __restrict__ cursor,
                                                      int* __restrict__ col, int E)
{
    int e = blockIdx.x * blockDim.x + threadIdx.x;
    if (e < E) {
        int d = dst[e];
        int pos = atomicAdd(&cursor[d], 1);
        col[pos] = src[e];
    }
}

// ---------------- operand conversion (bf16 hi/lo split) ----------------

__global__ __launch_bounds__(256) void conv_x(const float* __restrict__ x,
                                              ushort_t* __restrict__ Abig,
                                              int M, int M_pad)
{
    int id = blockIdx.x * blockDim.x + threadIdx.x;
    int r = id >> 7, q = id & 127;
    if (r >= M_pad) return;
    float4 v = make_float4(0.f, 0.f, 0.f, 0.f);
    if (r < M) v = *reinterpret_cast<const float4*>(&x[(size_t)r * 512 + q * 4]);
    ushort4 h, l;
    h.x = f2bf(v.x); l.x = f2bf(v.x - bf2f(h.x));
    h.y = f2bf(v.y); l.y = f2bf(v.y - bf2f(h.y));
    h.z = f2bf(v.z); l.z = f2bf(v.z - bf2f(h.z));
    h.w = f2bf(v.w); l.w = f2bf(v.w - bf2f(h.w));
    ushort_t* rowp = Abig + (size_t)r * 1024;
    *reinterpret_cast<ushort4*>(rowp + q * 4)       = h;
    *reinterpret_cast<ushort4*>(rowp + 512 + q * 4) = l;
}

// W0bigT (256 x 1536), row n: [hi(512) | hi(512) | lo(512)] of W0[:,n].
__global__ __launch_bounds__(256) void conv_w0(const float* __restrict__ W0,
                                               ushort_t* __restrict__ BT)
{
    int id = blockIdx.x * blockDim.x + threadIdx.x;
    int k = id & 511, n = id >> 9;
    if (n >= 256) return;
    float v = W0[(size_t)k * 256 + n];
    ushort_t h = f2bf(v);
    ushort_t l = f2bf(v - bf2f(h));
    ushort_t* rowp = BT + (size_t)n * 1536;
    rowp[k] = h; rowp[512 + k] = h; rowp[1024 + k] = l;
}

// W1bigT (128 x 768), row n: [hi(256) | hi(256) | lo(256)]; plus W1col fp32.
__global__ __launch_bounds__(256) void conv_w1(const float* __restrict__ W1,
                                               ushort_t* __restrict__ BT,
                                               float* __restrict__ W1col)
{
    int id = blockIdx.x * blockDim.x + threadIdx.x;
    int k = id & 255, n = id >> 8;
    if (n >= 128) return;
    float v = W1[(size_t)k * 129 + n];
    ushort_t h = f2bf(v);
    ushort_t l = f2bf(v - bf2f(h));
    ushort_t* rowp = BT + (size_t)n * 768;
    rowp[k] = h; rowp[256 + k] = h; rowp[512 + k] = l;
    if (n == 0) W1col[k] = W1[(size_t)k * 129 + 128];
}

// ---------------- MFMA GEMM: C = A(M x K eff) * BT(N x K)^T ----------------
// K iterates [0, K); A's k-index wraps at kwrap (so Ah reused for the Bl band).
// 128x128 tile, BK=32, 256 thr = 4 waves (2x2 of 64x64), 16x16x32 MFMA.
__global__ __launch_bounds__(256) void gemm_bf16(const ushort_t* __restrict__ A, int lda,
                                                 const ushort_t* __restrict__ BT, int ldbt,
                                                 float* __restrict__ C, int ldc,
                                                 int M, int K, int kwrap)
{
    __shared__ short As[128 * 32];
    __shared__ short Bs[128 * 32];

    int tid  = threadIdx.x;
    int w    = tid >> 6;
    int lane = tid & 63;
    int lm   = lane & 15;
    int lq   = lane >> 4;
    int bm   = blockIdx.x * 128;
    int bn   = blockIdx.y * 128;
    int wr   = (w >> 1) * 64;
    int wc   = (w & 1) * 64;

    f32x4 acc[4][4];
#pragma unroll
    for (int i = 0; i < 4; ++i)
#pragma unroll
        for (int j = 0; j < 4; ++j) acc[i][j] = (f32x4)(0.f);

    int srow = (lane >> 2);
    int scol = (lane & 3) * 16;

    for (int k0 = 0; k0 < K; k0 += 32) {
        int ka = (k0 < kwrap) ? k0 : (k0 - kwrap);   // A k-wrap (tiles never straddle)
#pragma unroll
        for (int q = 0; q < 2; ++q) {
            int r = w * 32 + q * 16 + srow;
            const char* ga = (const char*)A + ((size_t)(bm + r) * lda + ka) * 2 + scol;
            async_copy16(ga, (char*)As + (size_t)(w * 32 + q * 16) * 64);
        }
#pragma unroll
        for (int q = 0; q < 2; ++q) {
            int r = w * 32 + q * 16 + srow;
            const char* gb = (const char*)BT + ((size_t)(bn + r) * ldbt + k0) * 2 + scol;
            async_copy16(gb, (char*)Bs + (size_t)(w * 32 + q * 16) * 64);
        }
        __syncthreads();

        bf16x8 afr[4], bfr[4];
#pragma unroll
        for (int mi = 0; mi < 4; ++mi)
            afr[mi] = *reinterpret_cast<const bf16x8*>(&As[(wr + mi * 16 + lm) * 32 + lq * 8]);
#pragma unroll
        for (int ni = 0; ni < 4; ++ni)
            bfr[ni] = *reinterpret_cast<const bf16x8*>(&Bs[(wc + ni * 16 + lm) * 32 + lq * 8]);
#pragma unroll
        for (int mi = 0; mi < 4; ++mi)
#pragma unroll
            for (int ni = 0; ni < 4; ++ni)
                acc[mi][ni] = __builtin_amdgcn_mfma_f32_16x16x32_bf16(
                    afr[mi], bfr[ni], acc[mi][ni], 0, 0, 0);
        __syncthreads();
    }

#pragma unroll
    for (int mi = 0; mi < 4; ++mi) {
#pragma unroll
        for (int ni = 0; ni < 4; ++ni) {
            int rbase = bm + wr + mi * 16 + lq * 4;
            int cc    = bn + wc + ni * 16 + lm;
#pragma unroll
            for (int e = 0; e < 4; ++e) {
                int r = rbase + e;
                if (r < M) C[(size_t)r * ldc + cc] = acc[mi][ni][e];
            }
        }
    }
}

// ---------------- fused pieces ----------------

__device__ __forceinline__ float softplus_f(float x)
{
    return fmaxf(x, 0.f) + log1pf(expf(-fabsf(x)));
}

__device__ __forceinline__ void fma4(float4& a, float w, const float4& v)
{
    a.x = fmaf(w, v.x, a.x);
    a.y = fmaf(w, v.y, a.y);
    a.z = fmaf(w, v.z, a.z);
    a.w = fmaf(w, v.w, a.w);
}

// layer-1 aggregation + softplus -> H1big bf16 [hi(256) | lo(256)] per node.
// 4 waves = 4 edge slots x 64 float4-cols; inner loop 4x unrolled (4 loads in flight).
__global__ __launch_bounds__(256) void agg1_kernel(const float* __restrict__ T1,
                                                   const float* __restrict__ dinv,
                                                   const int* __restrict__ rowptr,
                                                   const int* __restrict__ col,
                                                   ushort_t* __restrict__ H1big, int N)
{
    int node = blockIdx.x;
    int tid  = threadIdx.x;
    int c    = tid & 63;
    int slot = tid >> 6;
    float di = dinv[node];
    int beg = rowptr[node], end = rowptr[node + 1];

    float4 acc = make_float4(0.f, 0.f, 0.f, 0.f);
    __shared__ int    s_src[256];
    __shared__ float  s_w[256];
    __shared__ float4 red[4][64];

    for (int base = beg; base < end; base += 256) {
        int cnt = min(256, end - base);
        if (tid < cnt) {
            int s = col[base + tid];
            s_src[tid] = s;
            s_w[tid]   = dinv[s];
        }
        __syncthreads();
        int jb = 0;
        int lim = cnt & ~15;
        for (; jb < lim; jb += 16) {
            int j0 = jb + slot, j1 = j0 + 4, j2 = j0 + 8, j3 = j0 + 12;
            int   s0 = s_src[j0], s1 = s_src[j1], s2 = s_src[j2], s3 = s_src[j3];
            float w0 = s_w[j0],  w1 = s_w[j1],  w2 = s_w[j2],  w3 = s_w[j3];
            float4 v0 = *reinterpret_cast<const float4*>(&T1[(size_t)s0 * 256 + c * 4]);
            float4 v1 = *reinterpret_cast<const float4*>(&T1[(size_t)s1 * 256 + c * 4]);
            float4 v2 = *reinterpret_cast<const float4*>(&T1[(size_t)s2 * 256 + c * 4]);
            float4 v3 = *reinterpret_cast<const float4*>(&T1[(size_t)s3 * 256 + c * 4]);
            fma4(acc, w0, v0); fma4(acc, w1, v1); fma4(acc, w2, v2); fma4(acc, w3, v3);
        }
        for (; jb < cnt; jb += 4) {
            int j = jb + slot;
            if (j < cnt) {
                int   s = s_src[j];
                float w = s_w[j];
                float4 v = *reinterpret_cast<const float4*>(&T1[(size_t)s * 256 + c * 4]);
                fma4(acc, w, v);
            }
        }
        __syncthreads();
    }

    red[slot][c] = acc;
    __syncthreads();
    if (slot == 0) {
        float4 a0 = red[0][c], a1 = red[1][c], a2 = red[2][c], a3 = red[3][c];
        float4 self = *reinterpret_cast<const float4*>(&T1[(size_t)node * 256 + c * 4]);
        float4 o;
        o.x = softplus_f((a0.x + a1.x + a2.x + a3.x + self.x * di) * di);
        o.y = softplus_f((a0.y + a1.y + a2.y + a3.y + self.y * di) * di);
        o.z = softplus_f((a0.z + a1.z + a2.z + a3.z + self.z * di) * di);
        o.w = softplus_f((a0.w + a1.w + a2.w + a3.w + self.w * di) * di);
        ushort4 h, l;
        h.x = f2bf(o.x); l.x = f2bf(o.x - bf2f(h.x));
        h.y = f2bf(o.y); l.y = f2bf(o.y - bf2f(h.y));
        h.z = f2bf(o.z); l.z = f2bf(o.z - bf2f(h.z));
        h.w = f2bf(o.w); l.w = f2bf(o.w - bf2f(h.w));
        ushort_t* rowp = H1big + (size_t)node * 512;
        *reinterpret_cast<ushort4*>(rowp + c * 4)       = h;
        *reinterpret_cast<ushort4*>(rowp + 256 + c * 4) = l;
    }
}

// kappa column: T2k[i] = dot(H1[i,:], W1col), H1 reconstructed hi+lo.
__global__ __launch_bounds__(256) void kappa_col_kernel(const ushort_t* __restrict__ H1big,
                                                        const float* __restrict__ W1col,
                                                        float* __restrict__ T2k, int N)
{
    __shared__ float w[256];
    int tid = threadIdx.x;
    w[tid] = W1col[tid];
    __syncthreads();
    int lane = tid & 63;
    int wid  = tid >> 6;
    int row  = blockIdx.x * 4 + wid;
    if (row >= N) return;
    const ushort_t* rowp = H1big + (size_t)row * 512;
    float s = 0.f;
#pragma unroll
    for (int k = lane; k < 256; k += 64) {
        float hv = bf2f(rowp[k]) + bf2f(rowp[256 + k]);
        s = fmaf(hv, w[k], s);
    }
#pragma unroll
    for (int off = 32; off > 0; off >>= 1)
        s += __shfl_down(s, off, 64);
    if (lane == 0) T2k[row] = s;
}

// layer-2 aggregation + softplus + Weibull epilogue. 8 slots x 32 float4-cols,
// inner loop 4x unrolled.
__global__ __launch_bounds__(256) void agg2_kernel(const float* __restrict__ T2,
                                                   const float* __restrict__ T2k,
                                                   const float* __restrict__ dinv,
                                                   const int* __restrict__ rowptr,
                                                   const int* __restrict__ col,
                                                   float* __restrict__ z_out,
                                                   float* __restrict__ lbd_out,
                                                   float* __restrict__ kap_out, int N)
{
    int node = blockIdx.x;
    int tid  = threadIdx.x;
    int c    = tid & 31;
    int slot = tid >> 5;        // 0..7
    float di = dinv[node];
    int beg = rowptr[node], end = rowptr[node + 1];

    float4 acc  = make_float4(0.f, 0.f, 0.f, 0.f);
    float  acck = 0.f;
    __shared__ int    s_src[256];
    __shared__ float  s_w[256];
    __shared__ float4 red[8][32];
    __shared__ float  s_kred[4];
    __shared__ float  s_g;

    for (int base = beg; base < end; base += 256) {
        int cnt = min(256, end - base);
        if (tid < cnt) {
            int s = col[base + tid];
            float w = dinv[s];
            s_src[tid] = s;
            s_w[tid]   = w;
            acck = fmaf(w, T2k[s], acck);
        }
        __syncthreads();
        int jb = 0;
        int lim = cnt & ~31;
        for (; jb < lim; jb += 32) {
            int j0 = jb + slot, j1 = j0 + 8, j2 = j0 + 16, j3 = j0 + 24;
            int   s0 = s_src[j0], s1 = s_src[j1], s2 = s_src[j2], s3 = s_src[j3];
            float w0 = s_w[j0],  w1 = s_w[j1],  w2 = s_w[j2],  w3 = s_w[j3];
            float4 v0 = *reinterpret_cast<const float4*>(&T2[(size_t)s0 * 128 + c * 4]);
            float4 v1 = *reinterpret_cast<const float4*>(&T2[(size_t)s1 * 128 + c * 4]);
            float4 v2 = *reinterpret_cast<const float4*>(&T2[(size_t)s2 * 128 + c * 4]);
            float4 v3 = *reinterpret_cast<const float4*>(&T2[(size_t)s3 * 128 + c * 4]);
            fma4(acc, w0, v0); fma4(acc, w1, v1); fma4(acc, w2, v2); fma4(acc, w3, v3);
        }
        for (; jb < cnt; jb += 8) {
            int j = jb + slot;
            if (j < cnt) {
                int   s = s_src[j];
                float w = s_w[j];
                float4 v = *reinterpret_cast<const float4*>(&T2[(size_t)s * 128 + c * 4]);
                fma4(acc, w, v);
            }
        }
        __syncthreads();
    }

#pragma unroll
    for (int off = 32; off > 0; off >>= 1)
        acck += __shfl_down(acck, off, 64);
    if ((tid & 63) == 0) s_kred[tid >> 6] = acck;

    red[slot][c] = acc;
    __syncthreads();

    if (tid == 0) {
        float ak = (s_kred[0] + s_kred[1] + s_kred[2] + s_kred[3] + T2k[node] * di) * di;
        float kv = softplus_f(ak) + 0.1f;
        s_g = expf(lgammaf(1.0f + 1.0f / kv));
        kap_out[node] = kv;
    }
    __syncthreads();

    if (slot == 0) {
        float4 a = red[0][c];
#pragma unroll
        for (int p = 1; p < 8; ++p) {
            float4 b = red[p][c];
            a.x += b.x; a.y += b.y; a.z += b.z; a.w += b.w;
        }
        float4 self = *reinterpret_cast<const float4*>(&T2[(size_t)node * 128 + c * 4]);
        float4 sp;
        sp.x = softplus_f((a.x + self.x * di) * di);
        sp.y = softplus_f((a.y + self.y * di) * di);
        sp.z = softplus_f((a.z + self.z * di) * di);
        sp.w = softplus_f((a.w + self.w * di) * di);
        float g = s_g;
        size_t o = (size_t)node * 128 + c * 4;
        *reinterpret_cast<float4*>(&lbd_out[o]) = sp;
        float4 zv = make_float4(sp.x * g, sp.y * g, sp.z * g, sp.w * g);
        *reinterpret_cast<float4*>(&z_out[o]) = zv;
    }
}

extern "C" void kernel_launch(void* const* d_in, const int* in_sizes, int n_in,
                              void* d_out, int out_size, void* d_ws, size_t ws_size,
                              hipStream_t stream)
{
    const float* x  = (const float*)d_in[0];
    const int*   ei = (const int*)d_in[1];
    const float* W0 = (const float*)d_in[2];
    const float* W1 = (const float*)d_in[3];

    const int N = in_sizes[0] / 512;      // 50000
    const int E = in_sizes[1] / 2;        // 1600000
    const int* src = ei;
    const int* dst = ei + E;

    const int mblocks = (N + 127) / 128;   // 391
    const int M_pad   = mblocks * 128;     // 50048
    const int nchunk  = (N + 1023) / 1024; // 49

    char* w = (char*)d_ws;
    size_t off = 0;
    auto take = [&](size_t bytes) -> void* {
        void* p = (void*)(w + off);
        off = (off + bytes + 255) & ~(size_t)255;
        return p;
    };
    int*      cnt    = (int*)take((size_t)N * 4);
    int*      rowptr = (int*)take((size_t)(N + 1) * 4);
    int*      cursor = (int*)take((size_t)N * 4);
    float*    dinv   = (float*)take((size_t)N * 4);
    int*      col    = (int*)take((size_t)E * 4);
    int*      blksum = (int*)take(64 * 4);
    int*      blkoff = (int*)take(64 * 4);
    ushort_t* W0bigT = (ushort_t*)take((size_t)256 * 1536 * 2);
    ushort_t* W1bigT = (ushort_t*)take((size_t)128 * 768 * 2);
    float*    W1col  = (float*)take((size_t)256 * 4);
    float*    T2k    = (float*)take((size_t)N * 4);
    float*    T1     = (float*)take((size_t)N * 256 * 4);
    float*    T2     = T1;                 // T1 dead after agg1; reuse
    ushort_t* Abig   = (ushort_t*)take((size_t)M_pad * 1024 * 2);   // 102.5 MB
    ushort_t* H1big  = Abig;               // alias: Abig dead after gemm1

    float* z_out   = (float*)d_out;
    float* lbd_out = z_out + (size_t)N * 128;
    float* kap_out = lbd_out + (size_t)N * 128;

    hipMemsetAsync(cnt, 0, (size_t)N * 4, stream);
    count_kernel<<<(E + 255) / 256, 256, 0, stream>>>(dst, cnt, E);
    scan_local<<<nchunk, 1024, 0, stream>>>(cnt, rowptr, dinv, blksum, N);
    scan_blk<<<1, 64, 0, stream>>>(blksum, blkoff, nchunk, rowptr, N);
    scan_add<<<(N + 255) / 256, 256, 0, stream>>>(rowptr, cursor, blkoff, N);
    scatter_kernel<<<(E + 255) / 256, 256, 0, stream>>>(src, dst, cursor, col, E);

    conv_x<<<(M_pad * 128) / 256, 256, 0, stream>>>(x, Abig, N, M_pad);
    conv_w0<<<(256 * 512) / 256, 256, 0, stream>>>(W0, W0bigT);
    conv_w1<<<(128 * 256) / 256, 256, 0, stream>>>(W1, W1bigT, W1col);

    // GEMM1: T1 = x @ W0, full bf16x3 split in one pass (K=1536, A wraps at 1024).
    dim3 g1(mblocks, 2);
    gemm_bf16<<<g1, 256, 0, stream>>>(Abig, 1024, W0bigT, 1536, T1, 256, N, 1536, 1024);

    agg1_kernel<<<N, 256, 0, stream>>>(T1, dinv, rowptr, col, H1big, N);

    // GEMM2: T2 = H1 @ W1main, one pass (K=768, A wraps at 512).
    dim3 g2(mblocks, 1);
    gemm_bf16<<<g2, 256, 0, stream>>>(H1big, 512, W1bigT, 768, T2, 128, N, 768, 512);

    kappa_col_kernel<<<(N + 3) / 4, 256, 0, stream>>>(H1big, W1col, T2k, N);
    agg2_kernel<<<N, 256, 0, stream>>>(T2, T2k, dinv, rowptr, col, z_out, lbd_out, kap_out, N);
}